// Round 10
// baseline (86.223 us; speedup 1.0000x reference)
//
#include <hip/hip_runtime.h>
#include <math.h>

// pred: (1,16,384,384) fp32, labels int32 same shape, area fp32[256]
constexpr int ZN = 16, YN = 384, XN = 384;
constexpr int NZ = 17, NY = 385, NX = 385;   // node grid
constexpr int NP = NY * NX;                  // 148225 nodes per z-slab
constexpr int NROWS = NZ * NY;               // 6545 node rows, one per wave
constexpr int BLOCKS = (NROWS + 3) / 4;      // 1637 blocks x 4 waves

__device__ __forceinline__ float sigm(float p) {
    return __fdividef(1.f, 1.f + __expf(-p));
}

__global__ __launch_bounds__(256) void sd_main(
        const float* __restrict__ pred,
        const int*   __restrict__ labels,
        const float* __restrict__ area,
        float*       __restrict__ partial)   // [num BLOCKS][den BLOCKS][vol BLOCKS]
{
    // Re-indexed LUT: idx = (own_col_nibble << 4) | prev_col_nibble, nibble bit r = 2dz+dy
    // (original corner k = dz*4+dy*2+dx; dx=0 prev col, dx=1 own col)
    __shared__ float s_area[256];
    {
        const int t = threadIdx.x;
        const int own = t >> 4, prv = t & 15;
        int code = 0;
#pragma unroll
        for (int r = 0; r < 4; ++r)
            code |= (((prv >> r) & 1) << (2 * r)) | (((own >> r) & 1) << (2 * r + 1));
        s_area[t] = area[code];
    }
    __syncthreads();

    const int lane = threadIdx.x & 63;
    // wave-uniform row id in SGPR -> scalar bases, saddr-form loads
    const int wid = __builtin_amdgcn_readfirstlane(blockIdx.x * 4 + (threadIdx.x >> 6));

    float num = 0.f, den = 0.f, vol = 0.f;

    if (wid < NROWS) {
        const int z = wid / NY;              // 0..16   (scalar)
        const int y = wid - z * NY;          // 0..384  (scalar)

        bool rv[4]; int cbase[4];
#pragma unroll
        for (int r = 0; r < 4; ++r) {
            const int zz = z - 1 + (r >> 1);
            const int yy = y - 1 + (r & 1);
            rv[r] = ((unsigned)zz < (unsigned)ZN) & ((unsigned)yy < (unsigned)YN);
            // clamped base: always in-bounds -> branchless loads; results masked by rv
            const int zc = min(max(zz, 0), ZN - 1);
            const int yc = min(max(yy, 0), YN - 1);
            cbase[r] = (zc * YN + yc) * XN;  // scalar
        }

        // ---- Phase 1: issue ALL loads up front (one latency exposure) ----
        float p[6][4]; int li[6][4];
#pragma unroll
        for (int j = 0; j < 6; ++j) {
            const int xo = j * 64 + lane;    // coalesced wave64 dword loads
#pragma unroll
            for (int r = 0; r < 4; ++r) {
                p[j][r]  = pred[cbase[r] + xo];
                li[j][r] = labels[cbase[r] + xo];
            }
        }

        // ---- Phase 2: per-column state (mask invalid rows with uniform rv) ----
        float S[6][4]; float Q[6]; int B[6];
#pragma unroll
        for (int j = 0; j < 6; ++j) {
            Q[j] = 0.f; B[j] = 0;
#pragma unroll
            for (int r = 0; r < 4; ++r) {
                float sv = sigm(p[j][r]);
                sv = rv[r] ? sv : 0.f;               // pad after sigmoid -> exactly 0
                const int lm = rv[r] ? li[j][r] : 0;
                S[j][r] = sv;
                const float d = sv - (float)lm;
                Q[j] = fmaf(d, d, Q[j]);
                // pred bit: pc > 0.5 (== p > 0 for valid; masked sv=0 -> false)
                B[j] |= (lm << r) | ((int)(sv > 0.5f) << (r + 4));
            }
        }

        auto node = [&](const float* sp, float qp, int bp,
                        const float* so, float qo, int bo) {
            const int idxL = ((bo & 15) << 4) | (bp & 15);
            const int idxP = (bo & 0xF0) | (bp >> 4);
            const float la = s_area[idxL];
            const float pa = s_area[idxP];
            num = fmaf(2.f * la, 1.f - (qp + qo) * 0.125f, num);
            den += la + pa;
            if (idxL == 0 || idxL == 255) {  // interior: all 8 labels uniform (~0.8%)
                const bool one = (idxL == 255);
                float b = 0.f;
#pragma unroll
                for (int r = 0; r < 4; ++r) {
                    b += __logf(fmaxf(one ? sp[r] : 1.f - sp[r], 1e-12f))
                       + __logf(fmaxf(one ? so[r] : 1.f - so[r], 1e-12f));
                }
                vol -= b;
            }
        };

        // ---- Phase 3: nodes; prev col = rotate-by-1, lane0 chains j-1 segment ----
        const int src = (lane + 63) & 63;
        const bool l0 = (lane == 0);
        float rp_s[4] = {0.f, 0.f, 0.f, 0.f};
        float rp_q = 0.f; int rp_b = 0;
#pragma unroll
        for (int j = 0; j < 6; ++j) {
            float ps[4], pq; int pb;
#pragma unroll
            for (int r = 0; r < 4; ++r) {
                const float ro = __shfl(S[j][r], src);
                ps[r] = l0 ? rp_s[r] : ro;
                rp_s[r] = ro;
            }
            {
                const float ro = __shfl(Q[j], src);
                pq = l0 ? rp_q : ro;
                rp_q = ro;
            }
            {
                const int ro = __shfl(B[j], src);
                pb = l0 ? rp_b : ro;
                rp_b = ro;
            }
            node(ps, pq, pb, S[j], Q[j], B[j]);
        }
        if (lane == 63) {                    // node x=384: prev = col 383, own = padding
            const float zs[4] = {0.f, 0.f, 0.f, 0.f};
            node(S[5], Q[5], B[5], zs, 0.f, 0);
        }
    }

    // wave + block reduction
#pragma unroll
    for (int off = 32; off > 0; off >>= 1) {
        num += __shfl_down(num, off);
        den += __shfl_down(den, off);
        vol += __shfl_down(vol, off);
    }
    __shared__ float rn[4], rd[4], rvv[4];
    const int w = threadIdx.x >> 6;
    if (lane == 0) { rn[w] = num; rd[w] = den; rvv[w] = vol; }
    __syncthreads();
    if (threadIdx.x == 0) {
        partial[blockIdx.x]              = rn[0] + rn[1] + rn[2] + rn[3];
        partial[BLOCKS + blockIdx.x]     = rd[0] + rd[1] + rd[2] + rd[3];
        partial[2 * BLOCKS + blockIdx.x] = rvv[0] + rvv[1] + rvv[2] + rvv[3];
    }
}

__global__ __launch_bounds__(256) void sd_final(
        const float* __restrict__ partial, float* __restrict__ out)
{
    double n = 0.0, d = 0.0, v = 0.0;
    for (int b = threadIdx.x; b < BLOCKS; b += 256) {
        n += (double)partial[b];
        d += (double)partial[BLOCKS + b];
        v += (double)partial[2 * BLOCKS + b];
    }
#pragma unroll
    for (int off = 32; off > 0; off >>= 1) {
        n += __shfl_down(n, off);
        d += __shfl_down(d, off);
        v += __shfl_down(v, off);
    }
    __shared__ double sn[4], sd_[4], sv[4];
    const int lane = threadIdx.x & 63, w = threadIdx.x >> 6;
    if (lane == 0) { sn[w] = n; sd_[w] = d; sv[w] = v; }
    __syncthreads();
    if (threadIdx.x == 0) {
        const double num = sn[0] + sn[1] + sn[2] + sn[3];
        const double den = sd_[0] + sd_[1] + sd_[2] + sd_[3];
        const double vol = (sv[0] + sv[1] + sv[2] + sv[3]) / (8.0 * (double)NP);
        const double dice = 1.0 - (num + 1e-3) / (den + 1e-3);
        out[0] = (float)(dice + vol);
    }
}

extern "C" void kernel_launch(void* const* d_in, const int* in_sizes, int n_in,
                              void* d_out, int out_size, void* d_ws, size_t ws_size,
                              hipStream_t stream)
{
    const float* pred   = (const float*)d_in[0];
    const int*   labels = (const int*)d_in[1];
    const float* area   = (const float*)d_in[2];
    float* out     = (float*)d_out;
    float* partial = (float*)d_ws;   // 3*BLOCKS floats, fully overwritten each call

    sd_main<<<BLOCKS, 256, 0, stream>>>(pred, labels, area, partial);
    sd_final<<<1, 256, 0, stream>>>(partial, out);
}